// Round 1
// baseline (838.080 us; speedup 1.0000x reference)
//
#include <hip/hip_runtime.h>
#include <hip/hip_bf16.h>

#define T_TOK 8192
#define NSLOT 16384
#define DM 512
#define DF 2048
#define NEXP 64
#define CAP 320

typedef __bf16 bf16_t;
typedef __bf16 bf16x8 __attribute__((ext_vector_type(8)));
typedef float floatx4 __attribute__((ext_vector_type(4)));

// ---------------- K1: scores -> expert ids (hash 0,1 only); also init inv = -1
__global__ __launch_bounds__(256) void k_scores(const float* __restrict__ x,
        const float* __restrict__ Wh, int* __restrict__ e_arr, int* __restrict__ inv)
{
    int tid = threadIdx.x;
    if (tid < 10) inv[blockIdx.x * 10 + tid] = -1;   // 2048*10 = 20480 = NEXP*CAP
    int wid = tid >> 6, lane = tid & 63;
    int t = blockIdx.x * 4 + wid;
    const float4* xp = (const float4*)(x + (size_t)t * DM);
    float4 x0 = xp[lane * 2], x1 = xp[lane * 2 + 1];
    const float4* w0p = (const float4*)(Wh);
    const float4* w1p = (const float4*)(Wh + DM);
    float4 a0 = w0p[lane * 2], a1 = w0p[lane * 2 + 1];
    float4 b0 = w1p[lane * 2], b1 = w1p[lane * 2 + 1];
    float s0 = x0.x*a0.x + x0.y*a0.y + x0.z*a0.z + x0.w*a0.w
             + x1.x*a1.x + x1.y*a1.y + x1.z*a1.z + x1.w*a1.w;
    float s1 = x0.x*b0.x + x0.y*b0.y + x0.z*b0.z + x0.w*b0.w
             + x1.x*b1.x + x1.y*b1.y + x1.z*b1.z + x1.w*b1.w;
    #pragma unroll
    for (int off = 32; off; off >>= 1) {
        s0 += __shfl_xor(s0, off);
        s1 += __shfl_xor(s1, off);
    }
    if (lane == 0) {
        int q0 = ((int)floorf(s0 * 8.0f)) & 63;   // python mod 64 == &63 (two's complement)
        int q1 = ((int)floorf(s1 * 8.0f)) & 63;
        e_arr[2 * t]     = q0;
        e_arr[2 * t + 1] = q1;
    }
}

// ---------------- K2: per-256-slot-chunk histogram + stable local rank
__global__ __launch_bounds__(256) void k_hist(const int* __restrict__ e_arr,
        int* __restrict__ rank_arr, int* __restrict__ hist_g)
{
    __shared__ int se[256];
    __shared__ int hist[64];
    int tid = threadIdx.x;
    if (tid < 64) hist[tid] = 0;
    __syncthreads();
    int s = blockIdx.x * 256 + tid;
    int e = e_arr[s];
    se[tid] = e;
    atomicAdd(&hist[e], 1);
    __syncthreads();
    int cnt = 0;
    for (int j = 0; j < 255; ++j)
        if (j < tid && se[j] == e) cnt++;
    rank_arr[s] = cnt;
    if (tid < 64) hist_g[blockIdx.x * 64 + tid] = hist[tid];
}

// ---------------- K3: exclusive scan over chunks -> global pos; build inverse map
__global__ __launch_bounds__(256) void k_pos(const int* __restrict__ e_arr,
        const int* __restrict__ rank_arr, const int* __restrict__ hist_g,
        int* __restrict__ pos_arr, int* __restrict__ inv)
{
    __shared__ int base[64][64];   // [chunk][expert]
    int tid = threadIdx.x;
    if (tid < 64) {
        int run = 0;
        for (int c = 0; c < 64; ++c) {
            base[c][tid] = run;
            run += hist_g[c * 64 + tid];
        }
    }
    __syncthreads();
    for (int i = 0; i < 64; ++i) {
        int s = i * 256 + tid;
        int e = e_arr[s];
        int p = base[s >> 8][e] + rank_arr[s];
        pos_arr[s] = p;
        if (p < CAP) inv[e * CAP + p] = s;
    }
}

// ---------------- K4: build buf (bf16), zero unfilled rows. One wave per (e,pos) row.
__global__ __launch_bounds__(256) void k_buf(const float* __restrict__ x,
        const int* __restrict__ inv, bf16_t* __restrict__ buf)
{
    int tid = threadIdx.x;
    int r = blockIdx.x * 4 + (tid >> 6);
    int lane = tid & 63;
    int s = inv[r];
    union { uint4 u; bf16_t h[8]; } pk;
    if (s >= 0) {
        int t = s >> 1;
        const float* xr = x + (size_t)t * DM + lane * 8;
        float4 f0 = *(const float4*)xr;
        float4 f1 = *(const float4*)(xr + 4);
        pk.h[0] = (bf16_t)f0.x; pk.h[1] = (bf16_t)f0.y;
        pk.h[2] = (bf16_t)f0.z; pk.h[3] = (bf16_t)f0.w;
        pk.h[4] = (bf16_t)f1.x; pk.h[5] = (bf16_t)f1.y;
        pk.h[6] = (bf16_t)f1.z; pk.h[7] = (bf16_t)f1.w;
    } else {
        pk.u.x = 0; pk.u.y = 0; pk.u.z = 0; pk.u.w = 0;
    }
    *(uint4*)(buf + (size_t)r * DM + lane * 8) = pk.u;
}

// ---------------- GEMM: C[e] = act(A[e](bf16, MxK) @ B[e](fp32, KxN) + bias[e])
// 128x128x64 tiles, 4 waves (64x64 each), mfma_f32_16x16x32_bf16.
template<int M_TOT, int N_DIM, int K_DIM, bool GELU, bool OUT_BF16>
__global__ __launch_bounds__(256) void gemm_expert(const bf16_t* __restrict__ A,
        const float* __restrict__ B, const float* __restrict__ bias,
        void* __restrict__ OutP)
{
    constexpr int MT = (M_TOT + 127) / 128;
    constexpr int NT = N_DIM / 128;
    int bx = blockIdx.x;
    int e  = bx / (MT * NT);
    int rem = bx % (MT * NT);
    int mt = rem / NT;
    int nt = rem % NT;

    const bf16_t* Ae = A + (size_t)e * M_TOT * K_DIM;
    const float*  Be = B + (size_t)e * K_DIM * N_DIM;
    const float*  be = bias + (size_t)e * N_DIM;

    __shared__ bf16_t As[128][72];   // [m][k], stride 72 -> conflict-free b128
    __shared__ bf16_t Bs[128][72];   // [n][k] (transposed during staging)

    int tid = threadIdx.x;
    int lane = tid & 63;
    int wid = tid >> 6;
    int wm = (wid >> 1) * 64;
    int wn = (wid & 1) * 64;
    int qm = lane & 15;
    int quad = lane >> 4;

    floatx4 acc[4][4];
    #pragma unroll
    for (int i = 0; i < 4; ++i)
        #pragma unroll
        for (int j = 0; j < 4; ++j) acc[i][j] = (floatx4)0.0f;

    int ac = tid & 7;           // A k-chunk (8 bf16 = 16B)
    int ar = tid >> 3;          // A row 0..31 (4 passes)
    int bkg = tid & 7;          // B k-group (8 k's)
    int bn0 = (tid >> 3) * 4;   // B n0: 0..124

    for (int kk = 0; kk < K_DIM; kk += 64) {
        // ---- stage A (bf16 global, row-major, K-contig) ----
        #pragma unroll
        for (int pr = 0; pr < 4; ++pr) {
            int row = pr * 32 + ar;
            int grow = mt * 128 + row;
            if (grow >= M_TOT) grow = M_TOT - 1;   // clamp; garbage rows guarded at store
            uint4 v = *(const uint4*)(Ae + (size_t)grow * K_DIM + kk + ac * 8);
            *(uint4*)(&As[row][ac * 8]) = v;
        }
        // ---- stage B: fp32 [K][N] -> bf16 [n][k] (transpose in regs) ----
        float4 bv[8];
        #pragma unroll
        for (int p = 0; p < 8; ++p) {
            int k = bkg * 8 + p;
            bv[p] = *(const float4*)(Be + (size_t)(kk + k) * N_DIM + nt * 128 + bn0);
        }
        #pragma unroll
        for (int i = 0; i < 4; ++i) {
            union { uint4 u; bf16_t h[8]; } pk;
            #pragma unroll
            for (int p = 0; p < 8; ++p)
                pk.h[p] = (bf16_t)(((const float*)&bv[p])[i]);
            *(uint4*)(&Bs[bn0 + i][bkg * 8]) = pk.u;
        }
        __syncthreads();
        // ---- compute ----
        #pragma unroll
        for (int ks = 0; ks < 2; ++ks) {
            bf16x8 af[4], bfr[4];
            #pragma unroll
            for (int i = 0; i < 4; ++i)
                af[i] = *(const bf16x8*)(&As[wm + i * 16 + qm][ks * 32 + quad * 8]);
            #pragma unroll
            for (int j = 0; j < 4; ++j)
                bfr[j] = *(const bf16x8*)(&Bs[wn + j * 16 + qm][ks * 32 + quad * 8]);
            #pragma unroll
            for (int i = 0; i < 4; ++i)
                #pragma unroll
                for (int j = 0; j < 4; ++j)
                    acc[i][j] = __builtin_amdgcn_mfma_f32_16x16x32_bf16(
                        af[i], bfr[j], acc[i][j], 0, 0, 0);
        }
        __syncthreads();
    }

    // ---- epilogue: bias (+gelu) ; C/D layout: col = lane&15, row = quad*4+r ----
    #pragma unroll
    for (int j = 0; j < 4; ++j) {
        int gn = nt * 128 + wn + j * 16 + qm;
        float bz = be[gn];
        #pragma unroll
        for (int i = 0; i < 4; ++i) {
            int rowBase = mt * 128 + wm + i * 16 + quad * 4;
            #pragma unroll
            for (int r = 0; r < 4; ++r) {
                int gm = rowBase + r;
                if (gm < M_TOT) {
                    float v = acc[i][j][r] + bz;
                    if (GELU) v = 0.5f * v * (1.0f + erff(v * 0.70710678118654752f));
                    size_t idx = (size_t)e * M_TOT * N_DIM + (size_t)gm * N_DIM + gn;
                    if (OUT_BF16) ((bf16_t*)OutP)[idx] = (bf16_t)v;
                    else          ((float*)OutP)[idx]  = v;
                }
            }
        }
    }
}

// ---------------- K7: gather + mean over the two slots
__global__ __launch_bounds__(256) void k_gather(const float* __restrict__ y,
        const int* __restrict__ e_arr, const int* __restrict__ pos_arr,
        float* __restrict__ out)
{
    int tid = threadIdx.x;
    int t = blockIdx.x * 4 + (tid >> 6);
    int lane = tid & 63;
    float a[8];
    #pragma unroll
    for (int i = 0; i < 8; ++i) a[i] = 0.0f;
    #pragma unroll
    for (int k = 0; k < 2; ++k) {
        int s = 2 * t + k;
        int e = e_arr[s], p = pos_arr[s];
        if (p < CAP) {
            const float* yr = y + ((size_t)e * CAP + p) * DM + lane * 8;
            float4 f0 = *(const float4*)yr;
            float4 f1 = *(const float4*)(yr + 4);
            a[0] += f0.x; a[1] += f0.y; a[2] += f0.z; a[3] += f0.w;
            a[4] += f1.x; a[5] += f1.y; a[6] += f1.z; a[7] += f1.w;
        }
    }
    float4 o0, o1;
    o0.x = a[0] * 0.5f; o0.y = a[1] * 0.5f; o0.z = a[2] * 0.5f; o0.w = a[3] * 0.5f;
    o1.x = a[4] * 0.5f; o1.y = a[5] * 0.5f; o1.z = a[6] * 0.5f; o1.w = a[7] * 0.5f;
    float* orow = out + (size_t)t * DM + lane * 8;
    *(float4*)orow = o0;
    *(float4*)(orow + 4) = o1;
}

extern "C" void kernel_launch(void* const* d_in, const int* in_sizes, int n_in,
                              void* d_out, int out_size, void* d_ws, size_t ws_size,
                              hipStream_t stream)
{
    const float* x  = (const float*)d_in[0];
    const float* Wh = (const float*)d_in[1];
    const float* W1 = (const float*)d_in[2];
    const float* b1 = (const float*)d_in[3];
    const float* W2 = (const float*)d_in[4];
    const float* b2 = (const float*)d_in[5];
    float* out = (float*)d_out;

    char* p = (char*)d_ws;
    int*    e_arr  = (int*)p;    p += (size_t)NSLOT * 4;
    int*    rank_a = (int*)p;    p += (size_t)NSLOT * 4;
    int*    hist_g = (int*)p;    p += (size_t)64 * 64 * 4;
    int*    pos_a  = (int*)p;    p += (size_t)NSLOT * 4;
    int*    inv    = (int*)p;    p += (size_t)NEXP * CAP * 4;
    bf16_t* buf    = (bf16_t*)p; p += (size_t)NEXP * CAP * DM * 2;
    bf16_t* hbuf   = (bf16_t*)p; p += (size_t)NEXP * CAP * DF * 2;
    float*  ybuf   = (float*)p;  p += (size_t)NEXP * CAP * DM * 4;

    k_scores<<<2048, 256, 0, stream>>>(x, Wh, e_arr, inv);
    k_hist<<<64, 256, 0, stream>>>(e_arr, rank_a, hist_g);
    k_pos<<<1, 256, 0, stream>>>(e_arr, rank_a, hist_g, pos_a, inv);
    k_buf<<<NEXP * CAP / 4, 256, 0, stream>>>(x, inv, buf);
    gemm_expert<CAP, DF, DM, true,  true ><<<NEXP * 3 * (DF / 128), 256, 0, stream>>>(buf, W1, b1, (void*)hbuf);
    gemm_expert<CAP, DM, DF, false, false><<<NEXP * 3 * (DM / 128), 256, 0, stream>>>(hbuf, W2, b2, (void*)ybuf);
    k_gather<<<2048, 256, 0, stream>>>(ybuf, e_arr, pos_a, out);
}